// Round 1
// baseline (2131.126 us; speedup 1.0000x reference)
//
#include <hip/hip_runtime.h>

#define D 96          // feature dim
#define D4 24         // float4s per row

// y = (1+eps) * x, elementwise over n4 float4s
__global__ void init_scale(const float* __restrict__ x, const float* __restrict__ eps_p,
                           float* __restrict__ y, int n4) {
    float s = 1.0f + eps_p[0];
    const float4* x4 = (const float4*)x;
    float4* y4 = (float4*)y;
    int i = blockIdx.x * blockDim.x + threadIdx.x;
    int stride = gridDim.x * blockDim.x;
    for (; i < n4; i += stride) {
        float4 v = x4[i];
        v.x *= s; v.y *= s; v.z *= s; v.w *= s;
        y4[i] = v;
    }
}

// agg[dst[e]] += feat[src[e]]  — one thread per (edge, 4-dim group)
__global__ void scatter_add(const float* __restrict__ feat, const int* __restrict__ src,
                            const int* __restrict__ dst, float* __restrict__ agg, int E) {
    int t = blockIdx.x * blockDim.x + threadIdx.x;
    int total = E * D4;
    if (t >= total) return;
    int e = t / D4;
    int g = t - e * D4;
    int s = src[e];
    int d = dst[e];
    const float4* f4 = (const float4*)feat;
    float4 v = f4[s * D4 + g];
    float* out = agg + d * D + g * 4;
    atomicAdd(out + 0, v.x);
    atomicAdd(out + 1, v.y);
    atomicAdd(out + 2, v.z);
    atomicAdd(out + 3, v.w);
}

// Y = relu(X @ W + b), X:[N,96] W:[96,96] b:[96]
// 64 rows per block, 256 threads; thread (r = tid>>2, tx = tid&3) computes
// 24 columns [tx*24, tx*24+24) of row r.
__global__ __launch_bounds__(256) void gemm_relu(const float* __restrict__ X,
                                                 const float* __restrict__ W,
                                                 const float* __restrict__ bias,
                                                 float* __restrict__ Y, int N) {
    __shared__ float Ws[D * D];        // 36864 B, row-major [k][c]
    __shared__ float Xs[64 * 100];     // pad 100: bank (4r+k)%32 -> <=2-way (free)

    int tid = threadIdx.x;

    // stage W: 2304 float4s, 9 per thread, coalesced
    const float4* W4 = (const float4*)W;
    float4* Ws4 = (float4*)Ws;
#pragma unroll
    for (int i = 0; i < 9; ++i) Ws4[tid + i * 256] = W4[tid + i * 256];

    // stage X tile: 64 rows x 24 float4 = 1536 float4s, 6 per thread
    int R0 = blockIdx.x * 64;
    const float4* X4 = (const float4*)X;
    int base4 = R0 * D4;
    int lim4 = N * D4;
#pragma unroll
    for (int i = 0; i < 6; ++i) {
        int f = tid + i * 256;             // 0..1535
        int row = f / D4;
        int col4 = f - row * D4;
        int gi = base4 + f;
        float4 v = make_float4(0.f, 0.f, 0.f, 0.f);
        if (gi < lim4) v = X4[gi];
        *(float4*)&Xs[row * 100 + col4 * 4] = v;
    }
    __syncthreads();

    int r = tid >> 2;            // 0..63
    int c0 = (tid & 3) * 24;     // 0,24,48,72

    float acc[24];
#pragma unroll
    for (int j = 0; j < 24; ++j) acc[j] = bias[c0 + j];

#pragma unroll 4
    for (int k = 0; k < D; ++k) {
        float xv = Xs[r * 100 + k];
        const float* wrow = &Ws[k * D + c0];   // 16B-aligned, -> ds_read_b128 x6
#pragma unroll
        for (int j = 0; j < 24; ++j) acc[j] += xv * wrow[j];
    }

    int row = R0 + r;
    if (row < N) {
        float* yr = Y + row * D + c0;
#pragma unroll
        for (int j = 0; j < 24; j += 4) {
            float4 v = make_float4(fmaxf(acc[j + 0], 0.f), fmaxf(acc[j + 1], 0.f),
                                   fmaxf(acc[j + 2], 0.f), fmaxf(acc[j + 3], 0.f));
            *(float4*)&yr[j] = v;
        }
    }
}

extern "C" void kernel_launch(void* const* d_in, const int* in_sizes, int n_in,
                              void* d_out, int out_size, void* d_ws, size_t ws_size,
                              hipStream_t stream) {
    const float* feat = (const float*)d_in[0];
    const int*   src  = (const int*)d_in[1];
    const int*   dst  = (const int*)d_in[2];
    const float* eps1 = (const float*)d_in[3];
    const float* W1a  = (const float*)d_in[4];
    const float* b1a  = (const float*)d_in[5];
    const float* W1b  = (const float*)d_in[6];
    const float* b1b  = (const float*)d_in[7];
    const float* eps2 = (const float*)d_in[8];
    const float* W2a  = (const float*)d_in[9];
    const float* b2a  = (const float*)d_in[10];
    const float* W2b  = (const float*)d_in[11];
    const float* b2b  = (const float*)d_in[12];

    int N = in_sizes[0] / D;     // 50000
    int E = in_sizes[1];         // 800000

    float* A   = (float*)d_ws;       // [N,96] scratch (19.2 MB)
    float* out = (float*)d_out;      // [N,96]

    int n4 = N * D4;
    int initGrid = (n4 + 255) / 256;
    int scatGrid = (E * D4 + 255) / 256;
    int gemmGrid = (N + 63) / 64;

    // ---- layer 1 ----
    // A = (1+eps1)*feat ; A += segment_sum(feat[src], dst)
    init_scale<<<initGrid, 256, 0, stream>>>(feat, eps1, A, n4);
    scatter_add<<<scatGrid, 256, 0, stream>>>(feat, src, dst, A, E);
    // out = relu(A @ W1a + b1a)
    gemm_relu<<<gemmGrid, 256, 0, stream>>>(A, W1a, b1a, out, N);
    // A = relu(out @ W1b + b1b)   -> h1
    gemm_relu<<<gemmGrid, 256, 0, stream>>>(out, W1b, b1b, A, N);

    // ---- layer 2 ----
    // out = (1+eps2)*h1 ; out += segment_sum(h1[src], dst)
    init_scale<<<initGrid, 256, 0, stream>>>(A, eps2, out, n4);
    scatter_add<<<scatGrid, 256, 0, stream>>>(A, src, dst, out, E);
    // A = relu(out @ W2a + b2a)
    gemm_relu<<<gemmGrid, 256, 0, stream>>>(out, W2a, b2a, A, N);
    // out = relu(A @ W2b + b2b)
    gemm_relu<<<gemmGrid, 256, 0, stream>>>(A, W2b, b2b, out, N);
}

// Round 2
// 299.678 us; speedup vs baseline: 7.1114x; 7.1114x over previous
//
#include <hip/hip_runtime.h>

#define D 96          // feature dim
#define D4 24         // float4s per row

// ======================= CSR build =======================

__global__ void hist_kernel(const int* __restrict__ dst, int* __restrict__ deg, int E) {
    int e = blockIdx.x * blockDim.x + threadIdx.x;
    if (e < E) atomicAdd(&deg[dst[e]], 1);
}

// pass A: per-block (1024 elems) sums
__global__ void block_sums(const int* __restrict__ deg, int* __restrict__ bsums, int N) {
    __shared__ int s[256];
    int t = threadIdx.x;
    int base = blockIdx.x * 1024 + t * 4;
    int sum = 0;
#pragma unroll
    for (int j = 0; j < 4; ++j) { int i = base + j; if (i < N) sum += deg[i]; }
    s[t] = sum; __syncthreads();
    for (int off = 128; off > 0; off >>= 1) {
        if (t < off) s[t] += s[t + off];
        __syncthreads();
    }
    if (t == 0) bsums[blockIdx.x] = s[0];
}

// pass B: serial scan of block sums (nb ~ 49), writes rowptr[N]=total
__global__ void scan_small(const int* __restrict__ bsums, int* __restrict__ boff,
                           int* __restrict__ total_out, int nb) {
    if (threadIdx.x == 0 && blockIdx.x == 0) {
        int acc = 0;
        for (int i = 0; i < nb; ++i) { boff[i] = acc; acc += bsums[i]; }
        *total_out = acc;
    }
}

// pass C: per-block exclusive scan + offset -> rowptr[0..N)
__global__ void scan_write(const int* __restrict__ deg, const int* __restrict__ boff,
                           int* __restrict__ rowptr, int N) {
    __shared__ int s[256];
    int t = threadIdx.x;
    int base = blockIdx.x * 1024 + t * 4;
    int v[4]; int tsum = 0;
#pragma unroll
    for (int j = 0; j < 4; ++j) { int i = base + j; v[j] = (i < N) ? deg[i] : 0; tsum += v[j]; }
    s[t] = tsum; __syncthreads();
    // Hillis-Steele inclusive scan over 256 thread sums (double-barrier form)
    for (int off = 1; off < 256; off <<= 1) {
        int x = (t >= off) ? s[t - off] : 0;
        __syncthreads();
        s[t] += x;
        __syncthreads();
    }
    int excl = s[t] - tsum + boff[blockIdx.x];
#pragma unroll
    for (int j = 0; j < 4; ++j) { int i = base + j; if (i < N) rowptr[i] = excl; excl += v[j]; }
}

// bucket fill: esrc[rowptr[d] + cursor[d]++] = src[e]
__global__ void fill_edges(const int* __restrict__ src, const int* __restrict__ dst,
                           const int* __restrict__ rowptr, int* __restrict__ cursor,
                           int* __restrict__ esrc, int E) {
    int e = blockIdx.x * blockDim.x + threadIdx.x;
    if (e >= E) return;
    int d = dst[e];
    int pos = rowptr[d] + atomicAdd(&cursor[d], 1);
    esrc[pos] = src[e];
}

// ======================= aggregation (gather) =======================
// Y[v] = (1+eps)*X[v] + sum_{e in [rowptr[v],rowptr[v+1])} X[esrc[e]]
// 24 threads per node, one float4 each; esrc load broadcasts across the group.
__global__ void gather_agg(const float* __restrict__ X, const int* __restrict__ rowptr,
                           const int* __restrict__ esrc, const float* __restrict__ eps_p,
                           float* __restrict__ Y, int N) {
    int t = blockIdx.x * blockDim.x + threadIdx.x;
    if (t >= N * D4) return;
    int v = t / D4;
    int g = t - v * D4;
    const float4* X4 = (const float4*)X;
    float s = 1.0f + eps_p[0];
    float4 x = X4[v * D4 + g];
    float4 acc = make_float4(x.x * s, x.y * s, x.z * s, x.w * s);
    int e = rowptr[v], e1 = rowptr[v + 1];
    // unroll-by-2: two independent gather loads in flight
    for (; e + 1 < e1; e += 2) {
        int u0 = esrc[e], u1 = esrc[e + 1];
        float4 m0 = X4[u0 * D4 + g];
        float4 m1 = X4[u1 * D4 + g];
        acc.x += m0.x; acc.y += m0.y; acc.z += m0.z; acc.w += m0.w;
        acc.x += m1.x; acc.y += m1.y; acc.z += m1.z; acc.w += m1.w;
    }
    if (e < e1) {
        int u = esrc[e];
        float4 m = X4[u * D4 + g];
        acc.x += m.x; acc.y += m.y; acc.z += m.z; acc.w += m.w;
    }
    ((float4*)Y)[v * D4 + g] = acc;
}

// ======================= fallback-path kernels (R1, proven) =======================

__global__ void init_scale(const float* __restrict__ x, const float* __restrict__ eps_p,
                           float* __restrict__ y, int n4) {
    float s = 1.0f + eps_p[0];
    const float4* x4 = (const float4*)x;
    float4* y4 = (float4*)y;
    int i = blockIdx.x * blockDim.x + threadIdx.x;
    int stride = gridDim.x * blockDim.x;
    for (; i < n4; i += stride) {
        float4 v = x4[i];
        v.x *= s; v.y *= s; v.z *= s; v.w *= s;
        y4[i] = v;
    }
}

__global__ void scatter_add(const float* __restrict__ feat, const int* __restrict__ src,
                            const int* __restrict__ dst, float* __restrict__ agg, int E) {
    int t = blockIdx.x * blockDim.x + threadIdx.x;
    int total = E * D4;
    if (t >= total) return;
    int e = t / D4;
    int g = t - e * D4;
    int s = src[e];
    int d = dst[e];
    const float4* f4 = (const float4*)feat;
    float4 v = f4[s * D4 + g];
    float* out = agg + d * D + g * 4;
    atomicAdd(out + 0, v.x);
    atomicAdd(out + 1, v.y);
    atomicAdd(out + 2, v.z);
    atomicAdd(out + 3, v.w);
}

// ======================= GEMM (unchanged from R1) =======================
// Y = relu(X @ W + b), X:[N,96] W:[96,96] b:[96]
__global__ __launch_bounds__(256) void gemm_relu(const float* __restrict__ X,
                                                 const float* __restrict__ W,
                                                 const float* __restrict__ bias,
                                                 float* __restrict__ Y, int N) {
    __shared__ float Ws[D * D];        // row-major [k][c]
    __shared__ float Xs[64 * 100];     // pad 100

    int tid = threadIdx.x;

    const float4* W4 = (const float4*)W;
    float4* Ws4 = (float4*)Ws;
#pragma unroll
    for (int i = 0; i < 9; ++i) Ws4[tid + i * 256] = W4[tid + i * 256];

    int R0 = blockIdx.x * 64;
    const float4* X4 = (const float4*)X;
    int base4 = R0 * D4;
    int lim4 = N * D4;
#pragma unroll
    for (int i = 0; i < 6; ++i) {
        int f = tid + i * 256;
        int row = f / D4;
        int col4 = f - row * D4;
        int gi = base4 + f;
        float4 v = make_float4(0.f, 0.f, 0.f, 0.f);
        if (gi < lim4) v = X4[gi];
        *(float4*)&Xs[row * 100 + col4 * 4] = v;
    }
    __syncthreads();

    int r = tid >> 2;
    int c0 = (tid & 3) * 24;

    float acc[24];
#pragma unroll
    for (int j = 0; j < 24; ++j) acc[j] = bias[c0 + j];

#pragma unroll 4
    for (int k = 0; k < D; ++k) {
        float xv = Xs[r * 100 + k];
        const float* wrow = &Ws[k * D + c0];
#pragma unroll
        for (int j = 0; j < 24; ++j) acc[j] += xv * wrow[j];
    }

    int row = R0 + r;
    if (row < N) {
        float* yr = Y + row * D + c0;
#pragma unroll
        for (int j = 0; j < 24; j += 4) {
            float4 v = make_float4(fmaxf(acc[j + 0], 0.f), fmaxf(acc[j + 1], 0.f),
                                   fmaxf(acc[j + 2], 0.f), fmaxf(acc[j + 3], 0.f));
            *(float4*)&yr[j] = v;
        }
    }
}

// ======================= launch =======================

extern "C" void kernel_launch(void* const* d_in, const int* in_sizes, int n_in,
                              void* d_out, int out_size, void* d_ws, size_t ws_size,
                              hipStream_t stream) {
    const float* feat = (const float*)d_in[0];
    const int*   src  = (const int*)d_in[1];
    const int*   dst  = (const int*)d_in[2];
    const float* eps1 = (const float*)d_in[3];
    const float* W1a  = (const float*)d_in[4];
    const float* b1a  = (const float*)d_in[5];
    const float* W1b  = (const float*)d_in[6];
    const float* b1b  = (const float*)d_in[7];
    const float* eps2 = (const float*)d_in[8];
    const float* W2a  = (const float*)d_in[9];
    const float* b2a  = (const float*)d_in[10];
    const float* W2b  = (const float*)d_in[11];
    const float* b2b  = (const float*)d_in[12];

    int N = in_sizes[0] / D;     // 50000
    int E = in_sizes[1];         // 800000

    float* out = (float*)d_out;

    // workspace carve-out (256B aligned)
    char* w = (char*)d_ws;
    size_t off = 0;
    auto carve = [&](size_t bytes) -> void* {
        void* p = w + off;
        off += (bytes + 255) & ~(size_t)255;
        return p;
    };
    float* A      = (float*)carve((size_t)N * D * sizeof(float));
    int*   rowptr = (int*)carve((size_t)(N + 1) * sizeof(int));
    int*   deg    = (int*)carve((size_t)N * sizeof(int));
    int*   cursor = (int*)carve((size_t)N * sizeof(int));
    int*   esrc   = (int*)carve((size_t)E * sizeof(int));
    int nb = (N + 1023) / 1024;
    int*   bsums  = (int*)carve((size_t)nb * sizeof(int));
    int*   boff   = (int*)carve((size_t)nb * sizeof(int));
    bool csr_ok = (off <= ws_size);

    int n4 = N * D4;
    int gatherGrid = (n4 + 255) / 256;
    int eGrid = (E + 255) / 256;
    int gemmGrid = (N + 63) / 64;

    if (csr_ok) {
        // ---- CSR build (int atomics only) ----
        hipMemsetAsync(deg, 0, (size_t)N * sizeof(int), stream);
        hipMemsetAsync(cursor, 0, (size_t)N * sizeof(int), stream);
        hist_kernel<<<eGrid, 256, 0, stream>>>(dst, deg, E);
        block_sums<<<nb, 256, 0, stream>>>(deg, bsums, N);
        scan_small<<<1, 64, 0, stream>>>(bsums, boff, rowptr + N, nb);
        scan_write<<<nb, 256, 0, stream>>>(deg, boff, rowptr, N);
        fill_edges<<<eGrid, 256, 0, stream>>>(src, dst, rowptr, cursor, esrc, E);

        // ---- layer 1 ----
        gather_agg<<<gatherGrid, 256, 0, stream>>>(feat, rowptr, esrc, eps1, A, N);
        gemm_relu<<<gemmGrid, 256, 0, stream>>>(A, W1a, b1a, out, N);
        gemm_relu<<<gemmGrid, 256, 0, stream>>>(out, W1b, b1b, A, N);   // h1 -> A

        // ---- layer 2 ----
        gather_agg<<<gatherGrid, 256, 0, stream>>>(A, rowptr, esrc, eps2, out, N);
        gemm_relu<<<gemmGrid, 256, 0, stream>>>(out, W2a, b2a, A, N);
        gemm_relu<<<gemmGrid, 256, 0, stream>>>(A, W2b, b2b, out, N);
    } else {
        // ---- fallback: R1 atomic-scatter path (needs only A) ----
        int initGrid = (n4 + 255) / 256;
        int scatGrid = (E * D4 + 255) / 256;
        init_scale<<<initGrid, 256, 0, stream>>>(feat, eps1, A, n4);
        scatter_add<<<scatGrid, 256, 0, stream>>>(feat, src, dst, A, E);
        gemm_relu<<<gemmGrid, 256, 0, stream>>>(A, W1a, b1a, out, N);
        gemm_relu<<<gemmGrid, 256, 0, stream>>>(out, W1b, b1b, A, N);
        init_scale<<<initGrid, 256, 0, stream>>>(A, eps2, out, n4);
        scatter_add<<<scatGrid, 256, 0, stream>>>(A, src, dst, out, E);
        gemm_relu<<<gemmGrid, 256, 0, stream>>>(out, W2a, b2a, A, N);
        gemm_relu<<<gemmGrid, 256, 0, stream>>>(A, W2b, b2b, out, N);
    }
}

// Round 3
// 272.562 us; speedup vs baseline: 7.8189x; 1.0995x over previous
//
#include <hip/hip_runtime.h>

#define D 96          // feature dim
#define D4 24         // float4s per row

// ======================= CSR build =======================

__global__ void hist_kernel(const int* __restrict__ dst, int* __restrict__ deg, int E) {
    int e = blockIdx.x * blockDim.x + threadIdx.x;
    if (e < E) atomicAdd(&deg[dst[e]], 1);
}

// pass A: per-block (1024 elems) sums
__global__ void block_sums(const int* __restrict__ deg, int* __restrict__ bsums, int N) {
    __shared__ int s[256];
    int t = threadIdx.x;
    int base = blockIdx.x * 1024 + t * 4;
    int sum = 0;
#pragma unroll
    for (int j = 0; j < 4; ++j) { int i = base + j; if (i < N) sum += deg[i]; }
    s[t] = sum; __syncthreads();
    for (int off = 128; off > 0; off >>= 1) {
        if (t < off) s[t] += s[t + off];
        __syncthreads();
    }
    if (t == 0) bsums[blockIdx.x] = s[0];
}

// pass B: serial scan of block sums (nb ~ 49)
__global__ void scan_small(const int* __restrict__ bsums, int* __restrict__ boff,
                           int* __restrict__ total_out, int nb) {
    if (threadIdx.x == 0 && blockIdx.x == 0) {
        int acc = 0;
        for (int i = 0; i < nb; ++i) { boff[i] = acc; acc += bsums[i]; }
        *total_out = acc;
    }
}

// pass C: per-block exclusive scan + offset -> rowptr[0..N)
__global__ void scan_write(const int* __restrict__ deg, const int* __restrict__ boff,
                           int* __restrict__ rowptr, int N) {
    __shared__ int s[256];
    int t = threadIdx.x;
    int base = blockIdx.x * 1024 + t * 4;
    int v[4]; int tsum = 0;
#pragma unroll
    for (int j = 0; j < 4; ++j) { int i = base + j; v[j] = (i < N) ? deg[i] : 0; tsum += v[j]; }
    s[t] = tsum; __syncthreads();
    for (int off = 1; off < 256; off <<= 1) {
        int x = (t >= off) ? s[t - off] : 0;
        __syncthreads();
        s[t] += x;
        __syncthreads();
    }
    int excl = s[t] - tsum + boff[blockIdx.x];
#pragma unroll
    for (int j = 0; j < 4; ++j) { int i = base + j; if (i < N) rowptr[i] = excl; excl += v[j]; }
}

// bucket fill: cursor pre-initialized to rowptr -> 2 random ops/edge instead of 3
__global__ void fill_edges(const int* __restrict__ src, const int* __restrict__ dst,
                           int* __restrict__ cursor, int* __restrict__ esrc, int E) {
    int e = blockIdx.x * blockDim.x + threadIdx.x;
    if (e >= E) return;
    int pos = atomicAdd(&cursor[dst[e]], 1);
    esrc[pos] = src[e];
}

// ======================= fused GIN layer =======================
// One block = 64 nodes, 256 threads. Thread (r=tid>>2, q=tid&3).
// Phase 1 (gather): g[k] = (1+eps)X[v, f4 k*4+q] + sum_u X[u, f4 k*4+q]  -> Xs
// Phase 2 (GEMMa):  acc = Xs_row @ Wa + ba, thread owns cols q*24..q*24+23
// Phase 3:          Xs_row = relu(acc); Ws <- Wb
// Phase 4 (GEMMb):  out = relu(Xs_row @ Wb + bb)
__global__ __launch_bounds__(256) void gin_layer_fused(
    const float* __restrict__ X, const int* __restrict__ rowptr,
    const int* __restrict__ esrc, const float* __restrict__ eps_p,
    const float* __restrict__ Wa, const float* __restrict__ ba,
    const float* __restrict__ Wb, const float* __restrict__ bb,
    float* __restrict__ Y, int N) {
    __shared__ float Ws[D * D];        // 36864 B, row-major [k][c]
    __shared__ float Xs[64 * 100];     // 25600 B, pad 100

    int tid = threadIdx.x;
    int R0 = blockIdx.x * 64;
    int r = tid >> 2;            // 0..63
    int q = tid & 3;             // 0..3
    int v = R0 + r;

    // stage Wa (coalesced, 9 float4 per thread)
    const float4* Wa4 = (const float4*)Wa;
    float4* Ws4 = (float4*)Ws;
#pragma unroll
    for (int i = 0; i < 9; ++i) Ws4[tid + i * 256] = Wa4[tid + i * 256];

    // ---- gather phase ----
    float4 g[6];
    if (v < N) {
        const float4* X4 = (const float4*)X;
        float s = 1.0f + eps_p[0];
        int base = v * D4;
#pragma unroll
        for (int k = 0; k < 6; ++k) {
            float4 x = X4[base + k * 4 + q];   // lanes q=0..3 -> 64B contiguous
            g[k] = make_float4(x.x * s, x.y * s, x.z * s, x.w * s);
        }
        int e = rowptr[v], e1 = rowptr[v + 1];
        for (; e + 1 < e1; e += 2) {
            int u0 = esrc[e] * D4, u1 = esrc[e + 1] * D4;
#pragma unroll
            for (int k = 0; k < 6; ++k) {
                float4 m0 = X4[u0 + k * 4 + q];
                float4 m1 = X4[u1 + k * 4 + q];
                g[k].x += m0.x + m1.x; g[k].y += m0.y + m1.y;
                g[k].z += m0.z + m1.z; g[k].w += m0.w + m1.w;
            }
        }
        if (e < e1) {
            int u = esrc[e] * D4;
#pragma unroll
            for (int k = 0; k < 6; ++k) {
                float4 m = X4[u + k * 4 + q];
                g[k].x += m.x; g[k].y += m.y; g[k].z += m.z; g[k].w += m.w;
            }
        }
    } else {
#pragma unroll
        for (int k = 0; k < 6; ++k) g[k] = make_float4(0.f, 0.f, 0.f, 0.f);
    }
#pragma unroll
    for (int k = 0; k < 6; ++k)
        *(float4*)&Xs[r * 100 + (k * 4 + q) * 4] = g[k];
    __syncthreads();

    // ---- GEMMa ----
    int c0 = q * 24;
    float acc[24];
#pragma unroll
    for (int j = 0; j < 24; ++j) acc[j] = ba[c0 + j];
#pragma unroll 4
    for (int k = 0; k < D; ++k) {
        float xv = Xs[r * 100 + k];
        const float* wrow = &Ws[k * D + c0];
#pragma unroll
        for (int j = 0; j < 24; ++j) acc[j] += xv * wrow[j];
    }
    __syncthreads();   // all reads of Ws/Xs done

    // ---- relu -> Xs ; stage Wb ----
#pragma unroll
    for (int j = 0; j < 24; j += 4) {
        float4 h = make_float4(fmaxf(acc[j + 0], 0.f), fmaxf(acc[j + 1], 0.f),
                               fmaxf(acc[j + 2], 0.f), fmaxf(acc[j + 3], 0.f));
        *(float4*)&Xs[r * 100 + c0 + j] = h;
    }
    const float4* Wb4 = (const float4*)Wb;
#pragma unroll
    for (int i = 0; i < 9; ++i) Ws4[tid + i * 256] = Wb4[tid + i * 256];
    __syncthreads();

    // ---- GEMMb ----
    float acc2[24];
#pragma unroll
    for (int j = 0; j < 24; ++j) acc2[j] = bb[c0 + j];
#pragma unroll 4
    for (int k = 0; k < D; ++k) {
        float xv = Xs[r * 100 + k];
        const float* wrow = &Ws[k * D + c0];
#pragma unroll
        for (int j = 0; j < 24; ++j) acc2[j] += xv * wrow[j];
    }

    if (v < N) {
        float* yr = Y + v * D + c0;
#pragma unroll
        for (int j = 0; j < 24; j += 4) {
            float4 o = make_float4(fmaxf(acc2[j + 0], 0.f), fmaxf(acc2[j + 1], 0.f),
                                   fmaxf(acc2[j + 2], 0.f), fmaxf(acc2[j + 3], 0.f));
            *(float4*)&yr[j] = o;
        }
    }
}

// ======================= fallback-path kernels (R1, proven) =======================

__global__ void init_scale(const float* __restrict__ x, const float* __restrict__ eps_p,
                           float* __restrict__ y, int n4) {
    float s = 1.0f + eps_p[0];
    const float4* x4 = (const float4*)x;
    float4* y4 = (float4*)y;
    int i = blockIdx.x * blockDim.x + threadIdx.x;
    int stride = gridDim.x * blockDim.x;
    for (; i < n4; i += stride) {
        float4 v = x4[i];
        v.x *= s; v.y *= s; v.z *= s; v.w *= s;
        y4[i] = v;
    }
}

__global__ void scatter_add(const float* __restrict__ feat, const int* __restrict__ src,
                            const int* __restrict__ dst, float* __restrict__ agg, int E) {
    int t = blockIdx.x * blockDim.x + threadIdx.x;
    int total = E * D4;
    if (t >= total) return;
    int e = t / D4;
    int g = t - e * D4;
    int s = src[e];
    int d = dst[e];
    const float4* f4 = (const float4*)feat;
    float4 v = f4[s * D4 + g];
    float* out = agg + d * D + g * 4;
    atomicAdd(out + 0, v.x);
    atomicAdd(out + 1, v.y);
    atomicAdd(out + 2, v.z);
    atomicAdd(out + 3, v.w);
}

__global__ __launch_bounds__(256) void gemm_relu(const float* __restrict__ X,
                                                 const float* __restrict__ W,
                                                 const float* __restrict__ bias,
                                                 float* __restrict__ Y, int N) {
    __shared__ float Ws[D * D];
    __shared__ float Xs[64 * 100];
    int tid = threadIdx.x;
    const float4* W4 = (const float4*)W;
    float4* Ws4 = (float4*)Ws;
#pragma unroll
    for (int i = 0; i < 9; ++i) Ws4[tid + i * 256] = W4[tid + i * 256];
    int R0 = blockIdx.x * 64;
    const float4* X4 = (const float4*)X;
    int base4 = R0 * D4;
    int lim4 = N * D4;
#pragma unroll
    for (int i = 0; i < 6; ++i) {
        int f = tid + i * 256;
        int row = f / D4;
        int col4 = f - row * D4;
        int gi = base4 + f;
        float4 v = make_float4(0.f, 0.f, 0.f, 0.f);
        if (gi < lim4) v = X4[gi];
        *(float4*)&Xs[row * 100 + col4 * 4] = v;
    }
    __syncthreads();
    int r = tid >> 2;
    int c0 = (tid & 3) * 24;
    float acc[24];
#pragma unroll
    for (int j = 0; j < 24; ++j) acc[j] = bias[c0 + j];
#pragma unroll 4
    for (int k = 0; k < D; ++k) {
        float xv = Xs[r * 100 + k];
        const float* wrow = &Ws[k * D + c0];
#pragma unroll
        for (int j = 0; j < 24; ++j) acc[j] += xv * wrow[j];
    }
    int row = R0 + r;
    if (row < N) {
        float* yr = Y + row * D + c0;
#pragma unroll
        for (int j = 0; j < 24; j += 4) {
            float4 v = make_float4(fmaxf(acc[j + 0], 0.f), fmaxf(acc[j + 1], 0.f),
                                   fmaxf(acc[j + 2], 0.f), fmaxf(acc[j + 3], 0.f));
            *(float4*)&yr[j] = v;
        }
    }
}

// ======================= launch =======================

extern "C" void kernel_launch(void* const* d_in, const int* in_sizes, int n_in,
                              void* d_out, int out_size, void* d_ws, size_t ws_size,
                              hipStream_t stream) {
    const float* feat = (const float*)d_in[0];
    const int*   src  = (const int*)d_in[1];
    const int*   dst  = (const int*)d_in[2];
    const float* eps1 = (const float*)d_in[3];
    const float* W1a  = (const float*)d_in[4];
    const float* b1a  = (const float*)d_in[5];
    const float* W1b  = (const float*)d_in[6];
    const float* b1b  = (const float*)d_in[7];
    const float* eps2 = (const float*)d_in[8];
    const float* W2a  = (const float*)d_in[9];
    const float* b2a  = (const float*)d_in[10];
    const float* W2b  = (const float*)d_in[11];
    const float* b2b  = (const float*)d_in[12];

    int N = in_sizes[0] / D;     // 50000
    int E = in_sizes[1];         // 800000

    float* out = (float*)d_out;

    // workspace carve-out (256B aligned)
    char* w = (char*)d_ws;
    size_t off = 0;
    auto carve = [&](size_t bytes) -> void* {
        void* p = w + off;
        off += (bytes + 255) & ~(size_t)255;
        return p;
    };
    float* A      = (float*)carve((size_t)N * D * sizeof(float));
    int*   rowptr = (int*)carve((size_t)(N + 1) * sizeof(int));
    int*   deg    = (int*)carve((size_t)N * sizeof(int));
    int*   cursor = (int*)carve((size_t)N * sizeof(int));
    int*   esrc   = (int*)carve((size_t)E * sizeof(int));
    int nb = (N + 1023) / 1024;
    int*   bsums  = (int*)carve((size_t)nb * sizeof(int));
    int*   boff   = (int*)carve((size_t)nb * sizeof(int));
    bool csr_ok = (off <= ws_size);

    int n4 = N * D4;
    int eGrid = (E + 255) / 256;
    int layerGrid = (N + 63) / 64;

    if (csr_ok) {
        // ---- CSR build ----
        hipMemsetAsync(deg, 0, (size_t)N * sizeof(int), stream);
        hist_kernel<<<eGrid, 256, 0, stream>>>(dst, deg, E);
        block_sums<<<nb, 256, 0, stream>>>(deg, bsums, N);
        scan_small<<<1, 64, 0, stream>>>(bsums, boff, rowptr + N, nb);
        scan_write<<<nb, 256, 0, stream>>>(deg, boff, rowptr, N);
        hipMemcpyAsync(cursor, rowptr, (size_t)N * sizeof(int),
                       hipMemcpyDeviceToDevice, stream);
        fill_edges<<<eGrid, 256, 0, stream>>>(src, dst, cursor, esrc, E);

        // ---- layer 1 (fused gather+MLP) -> A ----
        gin_layer_fused<<<layerGrid, 256, 0, stream>>>(feat, rowptr, esrc, eps1,
                                                       W1a, b1a, W1b, b1b, A, N);
        // ---- layer 2 -> out ----
        gin_layer_fused<<<layerGrid, 256, 0, stream>>>(A, rowptr, esrc, eps2,
                                                       W2a, b2a, W2b, b2b, out, N);
    } else {
        // ---- fallback: R1 atomic-scatter path (needs only A) ----
        int initGrid = (n4 + 255) / 256;
        int scatGrid = (E * D4 + 255) / 256;
        int gemmGrid = (N + 63) / 64;
        init_scale<<<initGrid, 256, 0, stream>>>(feat, eps1, A, n4);
        scatter_add<<<scatGrid, 256, 0, stream>>>(feat, src, dst, A, E);
        gemm_relu<<<gemmGrid, 256, 0, stream>>>(A, W1a, b1a, out, N);
        gemm_relu<<<gemmGrid, 256, 0, stream>>>(out, W1b, b1b, A, N);
        init_scale<<<initGrid, 256, 0, stream>>>(A, eps2, out, n4);
        scatter_add<<<scatGrid, 256, 0, stream>>>(A, src, dst, out, E);
        gemm_relu<<<gemmGrid, 256, 0, stream>>>(out, W2a, b2a, A, N);
        gemm_relu<<<gemmGrid, 256, 0, stream>>>(A, W2b, b2b, out, N);
    }
}

// Round 4
// 254.541 us; speedup vs baseline: 8.3724x; 1.0708x over previous
//
#include <hip/hip_runtime.h>

#define D 96          // feature dim
#define D4 24         // float4s per row
#define XSTR 100      // Xs row stride in floats (pad: even bank spread for stride-400B b128)

// ======================= CSR build =======================

__global__ void hist_kernel(const int* __restrict__ dst, int* __restrict__ deg, int E) {
    int e = blockIdx.x * blockDim.x + threadIdx.x;
    if (e < E) atomicAdd(&deg[dst[e]], 1);
}

__global__ void block_sums(const int* __restrict__ deg, int* __restrict__ bsums, int N) {
    __shared__ int s[256];
    int t = threadIdx.x;
    int base = blockIdx.x * 1024 + t * 4;
    int sum = 0;
#pragma unroll
    for (int j = 0; j < 4; ++j) { int i = base + j; if (i < N) sum += deg[i]; }
    s[t] = sum; __syncthreads();
    for (int off = 128; off > 0; off >>= 1) {
        if (t < off) s[t] += s[t + off];
        __syncthreads();
    }
    if (t == 0) bsums[blockIdx.x] = s[0];
}

__global__ void scan_small(const int* __restrict__ bsums, int* __restrict__ boff,
                           int* __restrict__ total_out, int nb) {
    if (threadIdx.x == 0 && blockIdx.x == 0) {
        int acc = 0;
        for (int i = 0; i < nb; ++i) { boff[i] = acc; acc += bsums[i]; }
        *total_out = acc;
    }
}

__global__ void scan_write(const int* __restrict__ deg, const int* __restrict__ boff,
                           int* __restrict__ rowptr, int N) {
    __shared__ int s[256];
    int t = threadIdx.x;
    int base = blockIdx.x * 1024 + t * 4;
    int v[4]; int tsum = 0;
#pragma unroll
    for (int j = 0; j < 4; ++j) { int i = base + j; v[j] = (i < N) ? deg[i] : 0; tsum += v[j]; }
    s[t] = tsum; __syncthreads();
    for (int off = 1; off < 256; off <<= 1) {
        int x = (t >= off) ? s[t - off] : 0;
        __syncthreads();
        s[t] += x;
        __syncthreads();
    }
    int excl = s[t] - tsum + boff[blockIdx.x];
#pragma unroll
    for (int j = 0; j < 4; ++j) { int i = base + j; if (i < N) rowptr[i] = excl; excl += v[j]; }
}

// bucket fill: cursor pre-initialized (copy of rowptr) -> 2 random ops/edge
__global__ void fill_edges(const int* __restrict__ src, const int* __restrict__ dst,
                           int* __restrict__ cursor, int* __restrict__ esrc, int E) {
    int e = blockIdx.x * blockDim.x + threadIdx.x;
    if (e >= E) return;
    int pos = atomicAdd(&cursor[dst[e]], 1);
    esrc[pos] = src[e];
}

// ======================= fused GIN layer =======================
// Block = 64 nodes, 256 threads (4 waves), LDS = Xs only (25.6 KB -> high occupancy).
// Gather:   thread (r=tid>>2, q=tid&3), coalesced 64B row chunks -> Xs (row-major, stride 100)
// MLP:      wave wq owns cols wq*24..+23 (W loads wave-uniform -> scalar/broadcast, NO LDS);
//           lane owns row=lane; X read as 1 ds_read_b128 per 4 k.
// Epilogue: stage to Xs, then (r,q)-mapped coalesced float4 stores.
__global__ __launch_bounds__(256) void gin_layer_fused(
    const float* __restrict__ X, const int* __restrict__ rowptr,
    const int* __restrict__ esrc, const float* __restrict__ eps_p,
    const float* __restrict__ Wa, const float* __restrict__ ba,
    const float* __restrict__ Wb, const float* __restrict__ bb,
    float* __restrict__ Y, int N) {
    __shared__ float Xs[64 * XSTR];    // 25600 B

    int tid = threadIdx.x;
    int R0 = blockIdx.x * 64;

    // ---------- gather ----------
    {
        int r = tid >> 2, q = tid & 3;
        int v = R0 + r;
        float4 g[6];
        if (v < N) {
            const float4* X4 = (const float4*)X;
            float s = 1.0f + eps_p[0];
            int base = v * D4;
#pragma unroll
            for (int k = 0; k < 6; ++k) {
                float4 x = X4[base + k * 4 + q];       // 4 q-lanes -> 64B contiguous
                g[k] = make_float4(x.x * s, x.y * s, x.z * s, x.w * s);
            }
            int e = rowptr[v], e1 = rowptr[v + 1];
            for (; e + 1 < e1; e += 2) {
                int u0 = esrc[e] * D4, u1 = esrc[e + 1] * D4;
#pragma unroll
                for (int k = 0; k < 6; ++k) {
                    float4 m0 = X4[u0 + k * 4 + q];
                    float4 m1 = X4[u1 + k * 4 + q];
                    g[k].x += m0.x + m1.x; g[k].y += m0.y + m1.y;
                    g[k].z += m0.z + m1.z; g[k].w += m0.w + m1.w;
                }
            }
            if (e < e1) {
                int u = esrc[e] * D4;
#pragma unroll
                for (int k = 0; k < 6; ++k) {
                    float4 m = X4[u + k * 4 + q];
                    g[k].x += m.x; g[k].y += m.y; g[k].z += m.z; g[k].w += m.w;
                }
            }
        } else {
#pragma unroll
            for (int k = 0; k < 6; ++k) g[k] = make_float4(0.f, 0.f, 0.f, 0.f);
        }
#pragma unroll
        for (int k = 0; k < 6; ++k)
            *(float4*)&Xs[r * XSTR + (k * 4 + q) * 4] = g[k];
    }
    __syncthreads();

    // ---------- MLP ----------
    int lane = tid & 63;
    int c0 = __builtin_amdgcn_readfirstlane(tid >> 6) * 24;   // wave-uniform col base

    // GEMMa: acc = Xs_row @ Wa + ba
    float acc[24];
#pragma unroll
    for (int j = 0; j < 24; ++j) acc[j] = ba[c0 + j];          // uniform -> scalar load
#pragma unroll 2
    for (int k0 = 0; k0 < D; k0 += 4) {
        float4 xv = *(const float4*)&Xs[lane * XSTR + k0];     // 1 b128 per 4 k
        const float* xf = (const float*)&xv;
#pragma unroll
        for (int kk = 0; kk < 4; ++kk) {
            float x = xf[kk];
            const float* wr = &Wa[(k0 + kk) * D + c0];          // wave-uniform address
#pragma unroll
            for (int j = 0; j < 24; ++j) acc[j] = fmaf(x, wr[j], acc[j]);
        }
    }
    __syncthreads();                       // all Xs(agg) reads done

    // h = relu(acc) -> Xs (wave writes its col slice of every row; disjoint)
#pragma unroll
    for (int j = 0; j < 24; j += 4) {
        float4 h = make_float4(fmaxf(acc[j + 0], 0.f), fmaxf(acc[j + 1], 0.f),
                               fmaxf(acc[j + 2], 0.f), fmaxf(acc[j + 3], 0.f));
        *(float4*)&Xs[lane * XSTR + c0 + j] = h;
    }
    __syncthreads();

    // GEMMb: acc2 = h_row @ Wb + bb
    float acc2[24];
#pragma unroll
    for (int j = 0; j < 24; ++j) acc2[j] = bb[c0 + j];
#pragma unroll 2
    for (int k0 = 0; k0 < D; k0 += 4) {
        float4 xv = *(const float4*)&Xs[lane * XSTR + k0];
        const float* xf = (const float*)&xv;
#pragma unroll
        for (int kk = 0; kk < 4; ++kk) {
            float x = xf[kk];
            const float* wr = &Wb[(k0 + kk) * D + c0];
#pragma unroll
            for (int j = 0; j < 24; ++j) acc2[j] = fmaf(x, wr[j], acc2[j]);
        }
    }
    __syncthreads();                       // all Xs(h) reads done

    // relu -> Xs, then coalesced copy-out
#pragma unroll
    for (int j = 0; j < 24; j += 4) {
        float4 o = make_float4(fmaxf(acc2[j + 0], 0.f), fmaxf(acc2[j + 1], 0.f),
                               fmaxf(acc2[j + 2], 0.f), fmaxf(acc2[j + 3], 0.f));
        *(float4*)&Xs[lane * XSTR + c0 + j] = o;
    }
    __syncthreads();
    {
        int r = tid >> 2, q = tid & 3;
        int v = R0 + r;
        if (v < N) {
            float4* Y4 = (float4*)Y;
#pragma unroll
            for (int k = 0; k < 6; ++k)
                Y4[v * D4 + k * 4 + q] = *(const float4*)&Xs[r * XSTR + (k * 4 + q) * 4];
        }
    }
}

// ======================= fallback-path kernels (R1, proven) =======================

__global__ void init_scale(const float* __restrict__ x, const float* __restrict__ eps_p,
                           float* __restrict__ y, int n4) {
    float s = 1.0f + eps_p[0];
    const float4* x4 = (const float4*)x;
    float4* y4 = (float4*)y;
    int i = blockIdx.x * blockDim.x + threadIdx.x;
    int stride = gridDim.x * blockDim.x;
    for (; i < n4; i += stride) {
        float4 v = x4[i];
        v.x *= s; v.y *= s; v.z *= s; v.w *= s;
        y4[i] = v;
    }
}

__global__ void scatter_add(const float* __restrict__ feat, const int* __restrict__ src,
                            const int* __restrict__ dst, float* __restrict__ agg, int E) {
    int t = blockIdx.x * blockDim.x + threadIdx.x;
    int total = E * D4;
    if (t >= total) return;
    int e = t / D4;
    int g = t - e * D4;
    int s = src[e];
    int d = dst[e];
    const float4* f4 = (const float4*)feat;
    float4 v = f4[s * D4 + g];
    float* out = agg + d * D + g * 4;
    atomicAdd(out + 0, v.x);
    atomicAdd(out + 1, v.y);
    atomicAdd(out + 2, v.z);
    atomicAdd(out + 3, v.w);
}

__global__ __launch_bounds__(256) void gemm_relu(const float* __restrict__ X,
                                                 const float* __restrict__ W,
                                                 const float* __restrict__ bias,
                                                 float* __restrict__ Y, int N) {
    __shared__ float Ws[D * D];
    __shared__ float Xs2[64 * XSTR];
    int tid = threadIdx.x;
    const float4* W4 = (const float4*)W;
    float4* Ws4 = (float4*)Ws;
#pragma unroll
    for (int i = 0; i < 9; ++i) Ws4[tid + i * 256] = W4[tid + i * 256];
    int R0 = blockIdx.x * 64;
    const float4* X4 = (const float4*)X;
    int base4 = R0 * D4;
    int lim4 = N * D4;
#pragma unroll
    for (int i = 0; i < 6; ++i) {
        int f = tid + i * 256;
        int row = f / D4;
        int col4 = f - row * D4;
        int gi = base4 + f;
        float4 v = make_float4(0.f, 0.f, 0.f, 0.f);
        if (gi < lim4) v = X4[gi];
        *(float4*)&Xs2[row * XSTR + col4 * 4] = v;
    }
    __syncthreads();
    int r = tid >> 2;
    int c0 = (tid & 3) * 24;
    float acc[24];
#pragma unroll
    for (int j = 0; j < 24; ++j) acc[j] = bias[c0 + j];
#pragma unroll 4
    for (int k = 0; k < D; ++k) {
        float xv = Xs2[r * XSTR + k];
        const float* wrow = &Ws[k * D + c0];
#pragma unroll
        for (int j = 0; j < 24; ++j) acc[j] += xv * wrow[j];
    }
    int row = R0 + r;
    if (row < N) {
        float* yr = Y + row * D + c0;
#pragma unroll
        for (int j = 0; j < 24; j += 4) {
            float4 v = make_float4(fmaxf(acc[j + 0], 0.f), fmaxf(acc[j + 1], 0.f),
                                   fmaxf(acc[j + 2], 0.f), fmaxf(acc[j + 3], 0.f));
            *(float4*)&yr[j] = v;
        }
    }
}

// ======================= launch =======================

extern "C" void kernel_launch(void* const* d_in, const int* in_sizes, int n_in,
                              void* d_out, int out_size, void* d_ws, size_t ws_size,
                              hipStream_t stream) {
    const float* feat = (const float*)d_in[0];
    const int*   src  = (const int*)d_in[1];
    const int*   dst  = (const int*)d_in[2];
    const float* eps1 = (const float*)d_in[3];
    const float* W1a  = (const float*)d_in[4];
    const float* b1a  = (const float*)d_in[5];
    const float* W1b  = (const float*)d_in[6];
    const float* b1b  = (const float*)d_in[7];
    const float* eps2 = (const float*)d_in[8];
    const float* W2a  = (const float*)d_in[9];
    const float* b2a  = (const float*)d_in[10];
    const float* W2b  = (const float*)d_in[11];
    const float* b2b  = (const float*)d_in[12];

    int N = in_sizes[0] / D;     // 50000
    int E = in_sizes[1];         // 800000

    float* out = (float*)d_out;

    // workspace carve-out (256B aligned)
    char* w = (char*)d_ws;
    size_t off = 0;
    auto carve = [&](size_t bytes) -> void* {
        void* p = w + off;
        off += (bytes + 255) & ~(size_t)255;
        return p;
    };
    float* A      = (float*)carve((size_t)N * D * sizeof(float));
    int*   rowptr = (int*)carve((size_t)(N + 1) * sizeof(int));
    int*   deg    = (int*)carve((size_t)N * sizeof(int));
    int*   cursor = (int*)carve((size_t)N * sizeof(int));
    int*   esrc   = (int*)carve((size_t)E * sizeof(int));
    int nb = (N + 1023) / 1024;
    int*   bsums  = (int*)carve((size_t)nb * sizeof(int));
    int*   boff   = (int*)carve((size_t)nb * sizeof(int));
    bool csr_ok = (off <= ws_size);

    int n4 = N * D4;
    int eGrid = (E + 255) / 256;
    int layerGrid = (N + 63) / 64;

    if (csr_ok) {
        // ---- CSR build ----
        hipMemsetAsync(deg, 0, (size_t)N * sizeof(int), stream);
        hist_kernel<<<eGrid, 256, 0, stream>>>(dst, deg, E);
        block_sums<<<nb, 256, 0, stream>>>(deg, bsums, N);
        scan_small<<<1, 64, 0, stream>>>(bsums, boff, rowptr + N, nb);
        scan_write<<<nb, 256, 0, stream>>>(deg, boff, rowptr, N);
        hipMemcpyAsync(cursor, rowptr, (size_t)N * sizeof(int),
                       hipMemcpyDeviceToDevice, stream);
        fill_edges<<<eGrid, 256, 0, stream>>>(src, dst, cursor, esrc, E);

        // ---- layer 1 -> A, layer 2 -> out ----
        gin_layer_fused<<<layerGrid, 256, 0, stream>>>(feat, rowptr, esrc, eps1,
                                                       W1a, b1a, W1b, b1b, A, N);
        gin_layer_fused<<<layerGrid, 256, 0, stream>>>(A, rowptr, esrc, eps2,
                                                       W2a, b2a, W2b, b2b, out, N);
    } else {
        // ---- fallback: R1 atomic-scatter path (needs only A) ----
        int initGrid = (n4 + 255) / 256;
        int scatGrid = (E * D4 + 255) / 256;
        int gemmGrid = (N + 63) / 64;
        init_scale<<<initGrid, 256, 0, stream>>>(feat, eps1, A, n4);
        scatter_add<<<scatGrid, 256, 0, stream>>>(feat, src, dst, A, E);
        gemm_relu<<<gemmGrid, 256, 0, stream>>>(A, W1a, b1a, out, N);
        gemm_relu<<<gemmGrid, 256, 0, stream>>>(out, W1b, b1b, A, N);
        init_scale<<<initGrid, 256, 0, stream>>>(A, eps2, out, n4);
        scatter_add<<<scatGrid, 256, 0, stream>>>(A, src, dst, out, E);
        gemm_relu<<<gemmGrid, 256, 0, stream>>>(out, W2a, b2a, A, N);
        gemm_relu<<<gemmGrid, 256, 0, stream>>>(A, W2b, b2b, out, N);
    }
}